// Round 5
// baseline (363.601 us; speedup 1.0000x reference)
//
#include <hip/hip_runtime.h>
#include <cstdint>
#include <cstddef>

#define N_COLS 4096
#define TPB 256
#define WPB 4                      // waves per block = rows per block (fully independent)
#define CSTR 260                   // words per histogram copy (bank-rotating stride)
#define SURV_CAP 64

// --- kernel 1: boost factors, double-precision exp rounded to fp32 ---
__global__ void boost_kernel(const float* __restrict__ dc,
                             const int* __restrict__ kp,
                             float* __restrict__ bf) {
    int i = blockIdx.x * blockDim.x + threadIdx.x;
    if (i < N_COLS) {
        float td = (float)kp[0] / (float)N_COLS;   // float32(k)/float32(n), like ref
        float arg = td - dc[i];                    // fp32 subtract, like ref
        bf[i] = (float)exp((double)arg);           // ~correctly-rounded fp32 exp
    }
}

__device__ __forceinline__ uint32_t orderable(uint32_t u) {
    return (u & 0x80000000u) ? ~u : (u | 0x80000000u);  // float order == uint order
}

// Wave-local LDS fence: each wave owns its histogram/survivor region, so
// ordering needs only lgkmcnt(0) within the wave — NO s_barrier anywhere.
__device__ __forceinline__ void wave_lgkm() {
    asm volatile("s_waitcnt lgkmcnt(0)" ::: "memory");
}

// One wave per row, ZERO block barriers, tiny register footprint:
// every phase re-reads x+bf from global (L1/L2/L3-hot after pass 1) and
// recomputes the boosted product (same inputs, same single v_mul ->
// bit-identical in every pass). This avoids both round-2's remat trap
// (no values are *expected* to stay live) and round-3's spill (nothing
// big is pinned). LDS is ~9.5 KB/block so __launch_bounds__(256,8) can
// reach 32 waves/CU; 32 independently-phased rows per CU keep the
// memory pipe busy while other waves sit in their selection chains.
__global__ __launch_bounds__(TPB, 8) void kwinner_kernel(
    const float* __restrict__ x, const float* __restrict__ bf,
    const int* __restrict__ kp, float* __restrict__ out, int rows)
{
    __shared__ __align__(16) uint32_t s_hist[WPB][2][CSTR];    // per-wave, 2 copies
    __shared__ uint32_t s_cand[WPB][SURV_CAP];                 // per-wave survivors
    __shared__ uint32_t s_m2[WPB * 8];                         // per-wave counter, bank-spread

    const int tid  = threadIdx.x;
    const int w    = tid >> 6;
    const int lane = tid & 63;

    size_t row = (size_t)blockIdx.x * WPB + (size_t)w;
    const size_t rmax = (size_t)rows - 1;     // ragged tail: clamp -> benign duplicate write
    if (row > rmax) row = rmax;

    const float4* xr   = (const float4*)(x + row * (size_t)N_COLS);
    float4*       orow = (float4*)(out + row * (size_t)N_COLS);
    const float4* bfr  = (const float4*)bf;   // 16 KB shared by all blocks: L2-resident

    uint32_t* hist = &s_hist[w][0][0];
    uint32_t* m2p  = &s_m2[w * 8];

    // clear my histogram (each lane: 4 bins per copy) + survivor counter
    {
        uint4 z; z.x = z.y = z.z = z.w = 0u;
        *(uint4*)&hist[4 * lane]        = z;
        *(uint4*)&hist[CSTR + 4 * lane] = z;
        if (lane == 0) *m2p = 0u;
    }
    wave_lgkm();

    // pass 1 (hist): stream the row, consume values AS THEY ARRIVE — the
    // wave is memory-active for nearly this whole phase. Composite digit
    // d = min((bits>>16) - 0x3F80, 255): monotone for all floats >= 1.0.
    const uint32_t cofs = (uint32_t)(lane & 1) * CSTR;   // 2 copies within the wave
    const float T0f = 1.10f;   // performance heuristic only; exactness guarded below
    #pragma unroll
    for (int jj = 0; jj < 16; ++jj) {
        float4 v = xr[lane + 64 * jj];
        float4 b = bfr[lane + 64 * jj];
        float p0 = v.x * b.x, p1 = v.y * b.y, p2 = v.z * b.z, p3 = v.w * b.w;
        if (p0 >= T0f) { uint32_t d = (__float_as_uint(p0) >> 16) - 0x3F80u; d = d > 255u ? 255u : d; atomicAdd(&hist[cofs + d], 1u); }
        if (p1 >= T0f) { uint32_t d = (__float_as_uint(p1) >> 16) - 0x3F80u; d = d > 255u ? 255u : d; atomicAdd(&hist[cofs + d], 1u); }
        if (p2 >= T0f) { uint32_t d = (__float_as_uint(p2) >> 16) - 0x3F80u; d = d > 255u ? 255u : d; atomicAdd(&hist[cofs + d], 1u); }
        if (p3 >= T0f) { uint32_t d = (__float_as_uint(p3) >> 16) - 0x3F80u; d = d > 255u ? 255u : d; atomicAdd(&hist[cofs + d], 1u); }
    }
    wave_lgkm();

    const uint32_t k = (uint32_t)kp[0];
    uint32_t rem = k;

    // per-wave copy-reduce + suffix-scan + digit pick (conflict-light uint4 reads)
    uint32_t dsel, packed;
    {
        uint4 a  = *(const uint4*)&hist[4 * lane];
        uint4 b2 = *(const uint4*)&hist[CSTR + 4 * lane];
        uint32_t vv0 = a.x + b2.x, vv1 = a.y + b2.y, vv2 = a.z + b2.z, vv3 = a.w + b2.w;
        uint32_t s3 = vv3, s2 = vv2 + s3, s1 = vv1 + s2, s0 = vv0 + s1;
        uint32_t T = s0;
        #pragma unroll
        for (int off = 1; off < 64; off <<= 1) {
            uint32_t t = (uint32_t)__shfl_down((int)T, off, 64);
            if (lane + off < 64) T += t;
        }
        uint32_t Tex = T - s0;   // sum over lanes > lane
        uint32_t S0 = Tex + s0, S1 = Tex + s1, S2 = Tex + s2, S3 = Tex + s3;
        int b = -1; uint32_t sn = 0;
        if (S3 >= rem)      { b = 3; sn = S3 - vv3; }
        else if (S2 >= rem) { b = 2; sn = S2 - vv2; }
        else if (S1 >= rem) { b = 1; sn = S1 - vv1; }
        else if (S0 >= rem) { b = 0; sn = S0 - vv0; }
        packed = (b >= 0) ? ((((uint32_t)(4 * lane + b + 1)) << 16) | sn) : 0u;
        #pragma unroll
        for (int off = 1; off < 64; off <<= 1) {
            uint32_t o = (uint32_t)__shfl_xor((int)packed, off, 64);
            packed = packed > o ? packed : o;
        }
        dsel = (packed >> 16) - 1u;      // selected digit (if packed != 0)
        rem -= (packed & 0xFFFFu);       // rank within selected bin
    }

    float thr = 0.0f;
    bool need_fallback = (packed == 0u) || (dsel == 255u);

    if (!need_fallback) {
        const uint32_t hi16 = 0x3F80u + dsel;
        // pass 2 (survivors): re-read row (cache-hot), recompute products
        // bit-identically, scatter bin members. May include a few elements
        // in [1.09375, T0) when dsel==0x0C — all strictly below every
        // histogrammed member, and rem <= member count, so the rem-th
        // largest is unaffected.
        #pragma unroll
        for (int jj = 0; jj < 16; ++jj) {
            float4 v = xr[lane + 64 * jj];
            float4 b = bfr[lane + 64 * jj];
            uint32_t u0 = __float_as_uint(v.x * b.x), u1 = __float_as_uint(v.y * b.y);
            uint32_t u2 = __float_as_uint(v.z * b.z), u3 = __float_as_uint(v.w * b.w);
            if ((u0 >> 16) == hi16) { uint32_t p = atomicAdd(m2p, 1u); if (p < SURV_CAP) s_cand[w][p] = u0; }
            if ((u1 >> 16) == hi16) { uint32_t p = atomicAdd(m2p, 1u); if (p < SURV_CAP) s_cand[w][p] = u1; }
            if ((u2 >> 16) == hi16) { uint32_t p = atomicAdd(m2p, 1u); if (p < SURV_CAP) s_cand[w][p] = u2; }
            if ((u3 >> 16) == hi16) { uint32_t p = atomicAdd(m2p, 1u); if (p < SURV_CAP) s_cand[w][p] = u3; }
        }
        wave_lgkm();
        const uint32_t m2 = *m2p;
        if (m2 <= SURV_CAP) {
            // per-wave 16-bit ballot descent over this wave's survivors
            uint32_t cv = ((uint32_t)lane < m2) ? s_cand[w][lane] : ((~hi16) << 16);
            uint32_t cur = 0;
            #pragma unroll
            for (int bpos = 15; bpos >= 0; --bpos) {
                uint32_t t  = (hi16 << 16) | cur | (1u << bpos);
                uint32_t mk = ~((1u << bpos) - 1u);
                uint32_t c  = (uint32_t)__popcll(__ballot(((cv ^ t) & mk) == 0u));
                if (c >= rem) cur |= (1u << bpos);
                else          rem -= c;
            }
            thr = __uint_as_float((hi16 << 16) | cur);
        } else {
            need_fallback = true;
        }
    }

    if (need_fallback) {
        // exact 4-pass orderable radix over all 4096 elements (any input),
        // wave-synchronous on this wave's private histogram; row re-read
        // each pass (rare path, cache-hot).
        {
            uint4 z; z.x = z.y = z.z = z.w = 0u;
            *(uint4*)&hist[4 * lane]        = z;
            *(uint4*)&hist[CSTR + 4 * lane] = z;
        }
        wave_lgkm();
        uint32_t prefix = 0;
        rem = k;
        const uint32_t pmasks[4] = {0u, 0xFF000000u, 0xFFFF0000u, 0xFFFFFF00u};
        #pragma unroll 1
        for (int pass = 0; pass < 4; ++pass) {
            const int shift = 24 - pass * 8;
            const uint32_t pm = pmasks[pass];
            #pragma unroll
            for (int jj = 0; jj < 16; ++jj) {
                float4 v = xr[lane + 64 * jj];
                float4 b = bfr[lane + 64 * jj];
                uint32_t ou;
                ou = orderable(__float_as_uint(v.x * b.x));
                if (((ou ^ prefix) & pm) == 0u) atomicAdd(&hist[cofs + ((ou >> shift) & 255u)], 1u);
                ou = orderable(__float_as_uint(v.y * b.y));
                if (((ou ^ prefix) & pm) == 0u) atomicAdd(&hist[cofs + ((ou >> shift) & 255u)], 1u);
                ou = orderable(__float_as_uint(v.z * b.z));
                if (((ou ^ prefix) & pm) == 0u) atomicAdd(&hist[cofs + ((ou >> shift) & 255u)], 1u);
                ou = orderable(__float_as_uint(v.w * b.w));
                if (((ou ^ prefix) & pm) == 0u) atomicAdd(&hist[cofs + ((ou >> shift) & 255u)], 1u);
            }
            wave_lgkm();
            uint4 a  = *(const uint4*)&hist[4 * lane];
            uint4 b2 = *(const uint4*)&hist[CSTR + 4 * lane];
            {
                uint4 z; z.x = z.y = z.z = z.w = 0u;
                *(uint4*)&hist[4 * lane]        = z;
                *(uint4*)&hist[CSTR + 4 * lane] = z;
            }
            wave_lgkm();   // zeros land before next pass's atomics
            uint32_t vv0 = a.x + b2.x, vv1 = a.y + b2.y, vv2 = a.z + b2.z, vv3 = a.w + b2.w;
            uint32_t s3 = vv3, s2 = vv2 + s3, s1 = vv1 + s2, s0 = vv0 + s1;
            uint32_t T = s0;
            #pragma unroll
            for (int off = 1; off < 64; off <<= 1) {
                uint32_t t = (uint32_t)__shfl_down((int)T, off, 64);
                if (lane + off < 64) T += t;
            }
            uint32_t Tex = T - s0;
            uint32_t S0 = Tex + s0, S1 = Tex + s1, S2 = Tex + s2, S3 = Tex + s3;
            int b = -1; uint32_t sn = 0;
            if (S3 >= rem)      { b = 3; sn = S3 - vv3; }
            else if (S2 >= rem) { b = 2; sn = S2 - vv2; }
            else if (S1 >= rem) { b = 1; sn = S1 - vv1; }
            else if (S0 >= rem) { b = 0; sn = S0 - vv0; }
            uint32_t pk = (b >= 0) ? ((((uint32_t)(4 * lane + b + 1)) << 16) | sn) : 0u;
            #pragma unroll
            for (int off = 1; off < 64; off <<= 1) {
                uint32_t o = (uint32_t)__shfl_xor((int)pk, off, 64);
                pk = pk > o ? pk : o;
            }
            prefix |= ((pk >> 16) - 1u) << shift;
            rem -= (pk & 0xFFFFu);
        }
        // orderable-space -> float bits
        uint32_t tu = (prefix & 0x80000000u) ? (prefix & 0x7FFFFFFFu) : ~prefix;
        thr = __uint_as_float(tu);
    }

    // pass 3 (epilogue): re-read row (cache-hot), recompute bit-identical
    // products, mask against thr, store.
    #pragma unroll
    for (int jj = 0; jj < 16; ++jj) {
        float4 v = xr[lane + 64 * jj];
        float4 b = bfr[lane + 64 * jj];
        float4 o;
        o.x = (v.x * b.x >= thr) ? v.x : 0.0f;
        o.y = (v.y * b.y >= thr) ? v.y : 0.0f;
        o.z = (v.z * b.z >= thr) ? v.z : 0.0f;
        o.w = (v.w * b.w >= thr) ? v.w : 0.0f;
        orow[lane + 64 * jj] = o;
    }
}

extern "C" void kernel_launch(void* const* d_in, const int* in_sizes, int n_in,
                              void* d_out, int out_size, void* d_ws, size_t ws_size,
                              hipStream_t stream) {
    const float* x  = (const float*)d_in[0];
    const float* dc = (const float*)d_in[1];
    const int*   kp = (const int*)d_in[2];
    float* out = (float*)d_out;
    float* bf  = (float*)d_ws;                 // 4096 floats of scratch

    const int n    = in_sizes[1];              // 4096
    const int rows = in_sizes[0] / n;          // 8192

    boost_kernel<<<(n + TPB - 1) / TPB, TPB, 0, stream>>>(dc, kp, bf);
    const int nb = (rows + WPB - 1) / WPB;     // 2048 blocks, 4 independent wave-rows each
    kwinner_kernel<<<nb, TPB, 0, stream>>>(x, bf, kp, out, rows);
}

// Round 6
// 234.760 us; speedup vs baseline: 1.5488x; 1.5488x over previous
//
#include <hip/hip_runtime.h>
#include <cstdint>
#include <cstddef>

#define N_COLS 4096
#define TPB 256
#define RPB 2                      // rows per block, processed CONCURRENTLY (ILP/MLP)
#define NCOPY 4                    // one histogram copy per wave
#define CSTR 260                   // words per copy (bank-rotating copy stride)
#define HWORDS (NCOPY * CSTR)      // 1040 words per row-histogram
#define SURV_CAP 64

// --- kernel 1: boost factors, double-precision exp rounded to fp32 ---
__global__ void boost_kernel(const float* __restrict__ dc,
                             const int* __restrict__ kp,
                             float* __restrict__ bf) {
    int i = blockIdx.x * blockDim.x + threadIdx.x;
    if (i < N_COLS) {
        float td = (float)kp[0] / (float)N_COLS;   // float32(k)/float32(n), like ref
        float arg = td - dc[i];                    // fp32 subtract, like ref
        bf[i] = (float)exp((double)arg);           // ~correctly-rounded fp32 exp
    }
}

__device__ __forceinline__ uint32_t orderable(uint32_t u) {
    return (u & 0x80000000u) ? ~u : (u | 0x80000000u);  // float order == uint order
}

// exact 4-pass orderable radix over one register-resident row (rare path;
// block-uniform entry). Products recomputed from registers (bit-identical).
__device__ __forceinline__ float radix_select(const float4 (&xv)[4], const float4 (&bb)[4],
    uint32_t* __restrict__ hist, int w, int lane, int tid, uint32_t k)
{
    {
        uint4* h4 = (uint4*)hist;
        uint4 z; z.x = z.y = z.z = z.w = 0u;
        #pragma unroll
        for (int i = 0; i < 2; ++i) { int idx = tid + i * TPB; if (idx < HWORDS / 4) h4[idx] = z; }
    }
    __syncthreads();
    uint32_t* hc = hist + (size_t)w * CSTR;
    uint32_t prefix = 0, rem = k;
    const uint32_t pmasks[4] = {0u, 0xFF000000u, 0xFFFF0000u, 0xFFFFFF00u};
    #pragma unroll 1
    for (int pass = 0; pass < 4; ++pass) {
        const int shift = 24 - pass * 8;
        const uint32_t pm = pmasks[pass];
        #pragma unroll
        for (int j = 0; j < 4; ++j) {
            uint32_t ou;
            ou = orderable(__float_as_uint(xv[j].x * bb[j].x));
            if (((ou ^ prefix) & pm) == 0u) atomicAdd(&hc[(ou >> shift) & 255u], 1u);
            ou = orderable(__float_as_uint(xv[j].y * bb[j].y));
            if (((ou ^ prefix) & pm) == 0u) atomicAdd(&hc[(ou >> shift) & 255u], 1u);
            ou = orderable(__float_as_uint(xv[j].z * bb[j].z));
            if (((ou ^ prefix) & pm) == 0u) atomicAdd(&hc[(ou >> shift) & 255u], 1u);
            ou = orderable(__float_as_uint(xv[j].w * bb[j].w));
            if (((ou ^ prefix) & pm) == 0u) atomicAdd(&hc[(ou >> shift) & 255u], 1u);
        }
        __syncthreads();
        uint32_t v0 = 0, v1 = 0, v2 = 0, v3 = 0;
        #pragma unroll
        for (int c = 0; c < NCOPY; ++c) {
            uint4 a = *(const uint4*)&hist[c * CSTR + 4 * lane];
            v0 += a.x; v1 += a.y; v2 += a.z; v3 += a.w;
        }
        __syncthreads();                    // all replicated reads done before zeroing
        {
            uint4* h4 = (uint4*)hist;
            uint4 z; z.x = z.y = z.z = z.w = 0u;
            #pragma unroll
            for (int i = 0; i < 2; ++i) { int idx = tid + i * TPB; if (idx < HWORDS / 4) h4[idx] = z; }
        }
        __syncthreads();
        uint32_t s3 = v3, s2 = v2 + s3, s1 = v1 + s2, s0 = v0 + s1;
        uint32_t T = s0;
        #pragma unroll
        for (int off = 1; off < 64; off <<= 1) {
            uint32_t t = (uint32_t)__shfl_down((int)T, off, 64);
            if (lane + off < 64) T += t;
        }
        uint32_t Tex = T - s0;
        uint32_t S0 = Tex + s0, S1 = Tex + s1, S2 = Tex + s2, S3 = Tex + s3;
        int b = -1; uint32_t sn = 0;
        if (S3 >= rem)      { b = 3; sn = S3 - v3; }
        else if (S2 >= rem) { b = 2; sn = S2 - v2; }
        else if (S1 >= rem) { b = 1; sn = S1 - v1; }
        else if (S0 >= rem) { b = 0; sn = S0 - v0; }
        uint32_t pk = (b >= 0) ? ((((uint32_t)(4 * lane + b + 1)) << 16) | sn) : 0u;
        #pragma unroll
        for (int off = 1; off < 64; off <<= 1) {
            uint32_t o = (uint32_t)__shfl_xor((int)pk, off, 64);
            pk = pk > o ? pk : o;
        }
        prefix |= ((pk >> 16) - 1u) << shift;
        rem -= (pk & 0xFFFFu);
    }
    uint32_t tu = (prefix & 0x80000000u) ? (prefix & 0x7FFFFFFFu) : ~prefix;
    return __uint_as_float(tu);
}

// Two rows per block, processed concurrently (fused shfl scans / ballot
// descents so cross-lane latencies overlap — round-4-proven +20% memory
// duty). Register policy (the round-6 change): keep only the RAW rows
// (xa, xc) and bf (bb) live — 48 floats, round-0-proven budget class —
// and recompute the product x*b at every use. The product is a single
// register-register v_mul: trivially rematerializable, so the allocator
// never reaches for memory (avoids round-2 load-remat and round-3 spill),
// and the epilogue touches no memory except the output stores (restores
// round-0's 65 MB FETCH / L3 reuse that round-4's epilogue re-read lost).
__global__ __launch_bounds__(TPB) void kwinner_kernel(
    const float* __restrict__ x, const float* __restrict__ bf,
    const int* __restrict__ kp, float* __restrict__ out, int rows)
{
    __shared__ __align__(16) uint32_t s_hist[RPB][NCOPY][CSTR];  // 8320 B
    __shared__ uint32_t s_cand[RPB][SURV_CAP];
    __shared__ uint32_t s_m2[RPB * 8];                           // counters, bank-spread

    const int tid  = threadIdx.x;
    const int lane = tid & 63;
    const int w    = tid >> 6;            // wave id = my histogram copy

    size_t rA = (size_t)blockIdx.x * RPB;
    size_t rB = rA + 1;
    const size_t rmax = (size_t)rows - 1;  // ragged tail: clamp -> benign duplicate
    if (rA > rmax) rA = rmax;
    if (rB > rmax) rB = rmax;

    const float4* xrA = (const float4*)(x + rA * (size_t)N_COLS);
    const float4* xrB = (const float4*)(x + rB * (size_t)N_COLS);
    float4* oA = (float4*)(out + rA * (size_t)N_COLS);
    float4* oB = (float4*)(out + rB * (size_t)N_COLS);
    const float4* bfr = (const float4*)bf;

    // burst-load both rows + bf (12 outstanding loads); these registers stay
    // live for the whole kernel — every later use is register-only.
    float4 xa[4], xc[4], bb[4];
    #pragma unroll
    for (int j = 0; j < 4; ++j) xa[j] = xrA[tid + j * TPB];
    #pragma unroll
    for (int j = 0; j < 4; ++j) xc[j] = xrB[tid + j * TPB];
    #pragma unroll
    for (int j = 0; j < 4; ++j) bb[j] = bfr[tid + j * TPB];

    // clear both histograms + counters
    {
        uint4* h4 = (uint4*)&s_hist[0][0][0];
        uint4 z; z.x = z.y = z.z = z.w = 0u;
        #pragma unroll
        for (int i = 0; i < 3; ++i) {
            int idx = tid + i * TPB;
            if (idx < (HWORDS * RPB) / 4) h4[idx] = z;
        }
        if (tid < RPB) s_m2[tid * 8] = 0u;
    }
    __syncthreads();

    // single histogram pass, both rows interleaved; composite digit
    // d = min((bits>>16) - 0x3F80, 255): monotone for all floats >= 1.0.
    const float T0f = 1.10f;   // performance heuristic only; exactness guarded below
    uint32_t* hA = &s_hist[0][w][0];
    uint32_t* hB = &s_hist[1][w][0];
    #pragma unroll
    for (int j = 0; j < 4; ++j) {
        float p0 = xa[j].x * bb[j].x, p1 = xa[j].y * bb[j].y;
        float p2 = xa[j].z * bb[j].z, p3 = xa[j].w * bb[j].w;
        float q0 = xc[j].x * bb[j].x, q1 = xc[j].y * bb[j].y;
        float q2 = xc[j].z * bb[j].z, q3 = xc[j].w * bb[j].w;
        if (p0 >= T0f) { uint32_t d = (__float_as_uint(p0) >> 16) - 0x3F80u; d = d > 255u ? 255u : d; atomicAdd(&hA[d], 1u); }
        if (p1 >= T0f) { uint32_t d = (__float_as_uint(p1) >> 16) - 0x3F80u; d = d > 255u ? 255u : d; atomicAdd(&hA[d], 1u); }
        if (p2 >= T0f) { uint32_t d = (__float_as_uint(p2) >> 16) - 0x3F80u; d = d > 255u ? 255u : d; atomicAdd(&hA[d], 1u); }
        if (p3 >= T0f) { uint32_t d = (__float_as_uint(p3) >> 16) - 0x3F80u; d = d > 255u ? 255u : d; atomicAdd(&hA[d], 1u); }
        if (q0 >= T0f) { uint32_t d = (__float_as_uint(q0) >> 16) - 0x3F80u; d = d > 255u ? 255u : d; atomicAdd(&hB[d], 1u); }
        if (q1 >= T0f) { uint32_t d = (__float_as_uint(q1) >> 16) - 0x3F80u; d = d > 255u ? 255u : d; atomicAdd(&hB[d], 1u); }
        if (q2 >= T0f) { uint32_t d = (__float_as_uint(q2) >> 16) - 0x3F80u; d = d > 255u ? 255u : d; atomicAdd(&hB[d], 1u); }
        if (q3 >= T0f) { uint32_t d = (__float_as_uint(q3) >> 16) - 0x3F80u; d = d > 255u ? 255u : d; atomicAdd(&hB[d], 1u); }
    }
    __syncthreads();

    const uint32_t k = (uint32_t)kp[0];
    uint32_t rem[2] = {k, k};
    uint32_t packed[2], dsel[2];
    {
        // copy-reduce (conflict-free stride-16B uint4 reads), both rows
        uint32_t vv[2][4];
        #pragma unroll
        for (int r = 0; r < 2; ++r) {
            uint32_t v0 = 0, v1 = 0, v2 = 0, v3 = 0;
            #pragma unroll
            for (int c = 0; c < NCOPY; ++c) {
                uint4 a = *(const uint4*)&s_hist[r][c][4 * lane];
                v0 += a.x; v1 += a.y; v2 += a.z; v3 += a.w;
            }
            vv[r][0] = v0; vv[r][1] = v1; vv[r][2] = v2; vv[r][3] = v3;
        }
        uint32_t s3[2], s2[2], s1[2], s0[2], T[2];
        #pragma unroll
        for (int r = 0; r < 2; ++r) {
            s3[r] = vv[r][3]; s2[r] = vv[r][2] + s3[r];
            s1[r] = vv[r][1] + s2[r]; s0[r] = vv[r][0] + s1[r];
            T[r] = s0[r];
        }
        // fused suffix-scan: the two rows' shfl latencies overlap
        #pragma unroll
        for (int off = 1; off < 64; off <<= 1) {
            uint32_t tA = (uint32_t)__shfl_down((int)T[0], off, 64);
            uint32_t tB = (uint32_t)__shfl_down((int)T[1], off, 64);
            if (lane + off < 64) { T[0] += tA; T[1] += tB; }
        }
        #pragma unroll
        for (int r = 0; r < 2; ++r) {
            uint32_t Tex = T[r] - s0[r];
            uint32_t S0 = Tex + s0[r], S1 = Tex + s1[r], S2 = Tex + s2[r], S3 = Tex + s3[r];
            int b = -1; uint32_t sn = 0;
            if (S3 >= rem[r])      { b = 3; sn = S3 - vv[r][3]; }
            else if (S2 >= rem[r]) { b = 2; sn = S2 - vv[r][2]; }
            else if (S1 >= rem[r]) { b = 1; sn = S1 - vv[r][1]; }
            else if (S0 >= rem[r]) { b = 0; sn = S0 - vv[r][0]; }
            packed[r] = (b >= 0) ? ((((uint32_t)(4 * lane + b + 1)) << 16) | sn) : 0u;
        }
        #pragma unroll
        for (int off = 1; off < 64; off <<= 1) {
            uint32_t oAx = (uint32_t)__shfl_xor((int)packed[0], off, 64);
            uint32_t oBx = (uint32_t)__shfl_xor((int)packed[1], off, 64);
            packed[0] = packed[0] > oAx ? packed[0] : oAx;
            packed[1] = packed[1] > oBx ? packed[1] : oBx;
        }
        dsel[0] = (packed[0] >> 16) - 1u;  rem[0] -= (packed[0] & 0xFFFFu);
        dsel[1] = (packed[1] >> 16) - 1u;  rem[1] -= (packed[1] & 0xFFFFu);
    }

    bool valid[2] = { packed[0] != 0u && dsel[0] != 255u,
                      packed[1] != 0u && dsel[1] != 255u };
    uint32_t hi16[2] = { 0x3F80u + dsel[0], 0x3F80u + dsel[1] };

    // scatter survivors for both rows (order irrelevant); products recomputed
    // bit-identically from registers. May include a few elements in
    // [1.09375, T0) when dsel==0x0C — all strictly below every histogrammed
    // member, so the rem-th largest is unaffected.
    if (valid[0]) {
        #pragma unroll
        for (int j = 0; j < 4; ++j) {
            uint32_t u0 = __float_as_uint(xa[j].x * bb[j].x), u1 = __float_as_uint(xa[j].y * bb[j].y);
            uint32_t u2 = __float_as_uint(xa[j].z * bb[j].z), u3 = __float_as_uint(xa[j].w * bb[j].w);
            if ((u0 >> 16) == hi16[0]) { uint32_t p = atomicAdd(&s_m2[0], 1u); if (p < SURV_CAP) s_cand[0][p] = u0; }
            if ((u1 >> 16) == hi16[0]) { uint32_t p = atomicAdd(&s_m2[0], 1u); if (p < SURV_CAP) s_cand[0][p] = u1; }
            if ((u2 >> 16) == hi16[0]) { uint32_t p = atomicAdd(&s_m2[0], 1u); if (p < SURV_CAP) s_cand[0][p] = u2; }
            if ((u3 >> 16) == hi16[0]) { uint32_t p = atomicAdd(&s_m2[0], 1u); if (p < SURV_CAP) s_cand[0][p] = u3; }
        }
    }
    if (valid[1]) {
        #pragma unroll
        for (int j = 0; j < 4; ++j) {
            uint32_t u0 = __float_as_uint(xc[j].x * bb[j].x), u1 = __float_as_uint(xc[j].y * bb[j].y);
            uint32_t u2 = __float_as_uint(xc[j].z * bb[j].z), u3 = __float_as_uint(xc[j].w * bb[j].w);
            if ((u0 >> 16) == hi16[1]) { uint32_t p = atomicAdd(&s_m2[8], 1u); if (p < SURV_CAP) s_cand[1][p] = u0; }
            if ((u1 >> 16) == hi16[1]) { uint32_t p = atomicAdd(&s_m2[8], 1u); if (p < SURV_CAP) s_cand[1][p] = u1; }
            if ((u2 >> 16) == hi16[1]) { uint32_t p = atomicAdd(&s_m2[8], 1u); if (p < SURV_CAP) s_cand[1][p] = u2; }
            if ((u3 >> 16) == hi16[1]) { uint32_t p = atomicAdd(&s_m2[8], 1u); if (p < SURV_CAP) s_cand[1][p] = u3; }
        }
    }
    __syncthreads();
    uint32_t m2[2] = { s_m2[0], s_m2[8] };
    if (m2[0] > SURV_CAP) valid[0] = false;
    if (m2[1] > SURV_CAP) valid[1] = false;

    // fused replicated 16-bit ballot descent (both rows per iteration).
    // Invalid rows run with a never-matching sentinel; result discarded.
    float thr[2] = {0.0f, 0.0f};
    {
        uint32_t cv[2], cur[2] = {0u, 0u}, rr[2] = { rem[0], rem[1] };
        #pragma unroll
        for (int r = 0; r < 2; ++r)
            cv[r] = (valid[r] && (uint32_t)lane < m2[r]) ? s_cand[r][lane]
                                                         : ((~hi16[r]) << 16);
        #pragma unroll
        for (int bpos = 15; bpos >= 0; --bpos) {
            uint32_t mk = ~((1u << bpos) - 1u);
            uint32_t tA = (hi16[0] << 16) | cur[0] | (1u << bpos);
            uint32_t tB = (hi16[1] << 16) | cur[1] | (1u << bpos);
            uint32_t cA = (uint32_t)__popcll(__ballot(((cv[0] ^ tA) & mk) == 0u));
            uint32_t cB = (uint32_t)__popcll(__ballot(((cv[1] ^ tB) & mk) == 0u));
            if (cA >= rr[0]) cur[0] |= (1u << bpos); else rr[0] -= cA;
            if (cB >= rr[1]) cur[1] |= (1u << bpos); else rr[1] -= cB;
        }
        if (valid[0]) thr[0] = __uint_as_float((hi16[0] << 16) | cur[0]);
        if (valid[1]) thr[1] = __uint_as_float((hi16[1] << 16) | cur[1]);
    }

    // rare exact fallback; conditions are block-uniform (replicated scan)
    if (!valid[0]) thr[0] = radix_select(xa, bb, &s_hist[0][0][0], w, lane, tid, k);
    if (!valid[1]) thr[1] = radix_select(xc, bb, &s_hist[1][0][0], w, lane, tid, k);

    // epilogue: pure-register mask + store — NO memory reads (restores
    // round-0's L3-reuse FETCH profile)
    #pragma unroll
    for (int j = 0; j < 4; ++j) {
        float4 o;
        o.x = (xa[j].x * bb[j].x >= thr[0]) ? xa[j].x : 0.0f;
        o.y = (xa[j].y * bb[j].y >= thr[0]) ? xa[j].y : 0.0f;
        o.z = (xa[j].z * bb[j].z >= thr[0]) ? xa[j].z : 0.0f;
        o.w = (xa[j].w * bb[j].w >= thr[0]) ? xa[j].w : 0.0f;
        oA[tid + j * TPB] = o;
        float4 p;
        p.x = (xc[j].x * bb[j].x >= thr[1]) ? xc[j].x : 0.0f;
        p.y = (xc[j].y * bb[j].y >= thr[1]) ? xc[j].y : 0.0f;
        p.z = (xc[j].z * bb[j].z >= thr[1]) ? xc[j].z : 0.0f;
        p.w = (xc[j].w * bb[j].w >= thr[1]) ? xc[j].w : 0.0f;
        oB[tid + j * TPB] = p;
    }
}

extern "C" void kernel_launch(void* const* d_in, const int* in_sizes, int n_in,
                              void* d_out, int out_size, void* d_ws, size_t ws_size,
                              hipStream_t stream) {
    const float* x  = (const float*)d_in[0];
    const float* dc = (const float*)d_in[1];
    const int*   kp = (const int*)d_in[2];
    float* out = (float*)d_out;
    float* bf  = (float*)d_ws;                 // 4096 floats of scratch

    const int n    = in_sizes[1];              // 4096
    const int rows = in_sizes[0] / n;          // 8192

    boost_kernel<<<(n + TPB - 1) / TPB, TPB, 0, stream>>>(dc, kp, bf);
    const int nb = (rows + RPB - 1) / RPB;     // 4096 blocks, 2 concurrent rows each
    kwinner_kernel<<<nb, TPB, 0, stream>>>(x, bf, kp, out, rows);
}